// Round 7
// baseline (142.740 us; speedup 1.0000x reference)
//
#include <hip/hip_runtime.h>
#include <hip/hip_bf16.h>
#include <hip/hip_fp16.h>

// Problem: B=8192, T=128, D=7, I=128, C=10, H=64, L=128
// ws layout (float slots):
//   sTh   fp16 [896][8192]   off 0          (3,670,016)
//   attnB fp16 [8192][128]   off 3,670,016  (524,288)
//   LPb   bf16 B-frags       off 4,194,304  (262,144)
//   partial [16][8192][10]   off 4,456,448  (1,310,720)
// total 5,767,168 floats = 23.1 MB

#define BB 8192
#define TT 128
#define II 128
#define CC 10
#define HH 64

#define OFF_S   0
#define OFF_AT  3670016
#define OFF_LPB 4194304
#define OFF_PT  4456448

typedef __attribute__((ext_vector_type(8))) short short8;
typedef __attribute__((ext_vector_type(16))) float floatx16;

static __device__ inline unsigned int pkbf(float lo, float hi) {
  __hip_bfloat162 h = __float22bfloat162_rn(make_float2(lo, hi));
  unsigned int u;
  __builtin_memcpy(&u, &h, 4);
  return u;
}

static __device__ inline short8 cvt8(float4 a, float4 b) {
  union { short8 v; unsigned int u[4]; } r;
  r.u[0] = pkbf(a.x, a.y);
  r.u[1] = pkbf(a.z, a.w);
  r.u[2] = pkbf(b.x, b.y);
  r.u[3] = pkbf(b.z, b.w);
  return r.v;
}

// ---------------- Phase 1: fused attn (MFMA) + zs (MFMA) + prep -------------
// blocks [0,64): attn | [64,960): zs | [960,1024): prep
__global__ __launch_bounds__(256, 4) void phase1_kernel(
    const float* __restrict__ x, const float* __restrict__ mask,
    const float* __restrict__ thr, const float* __restrict__ lo,
    const float* __restrict__ W1, const float* __restrict__ b1,
    const float* __restrict__ W2, const float* __restrict__ b2,
    __half* __restrict__ sTh, __half* __restrict__ attnB,
    unsigned int* __restrict__ lpb) {
  __shared__ float smem[8704];   // 34.8 KB
  const int blk = blockIdx.x;
  const int tid = threadIdx.x;
  const int wv = tid >> 6, lane = tid & 63;
  const int half = lane >> 5, l31 = lane & 31;

  if (blk < 64) {
    // ---------------- attn branch: 128 b-rows/block, 32/wave ----------------
    const int b0 = blk * 128 + wv * 32;

    // x A-frags (rows b0..b0+31, k=0..127)
    short8 axf[8];
    const float* xrow = x + (size_t)(b0 + l31) * II + half * 8;
#pragma unroll
    for (int s = 0; s < 8; ++s)
      axf[s] = cvt8(*(const float4*)(xrow + s * 16),
                    *(const float4*)(xrow + s * 16 + 4));

    // hidden = relu(x@W1 + b1): 2 n-tiles x 8 k-slices
    floatx16 acch[2];
#pragma unroll
    for (int i = 0; i < 16; ++i) { acch[0][i] = 0.f; acch[1][i] = 0.f; }
#pragma unroll
    for (int s = 0; s < 8; ++s) {
#pragma unroll
      for (int tile = 0; tile < 2; ++tile) {
        union { short8 v; unsigned int u[4]; } wf;
#pragma unroll
        for (int jp = 0; jp < 4; ++jp) {
          int k0 = s * 16 + half * 8 + jp * 2;
          float f0 = W1[(size_t)k0 * HH + tile * 32 + l31];
          float f1 = W1[(size_t)(k0 + 1) * HH + tile * 32 + l31];
          wf.u[jp] = pkbf(f0, f1);
        }
        acch[tile] = __builtin_amdgcn_mfma_f32_32x32x16_bf16(
            axf[s], wf.v, acch[tile], 0, 0, 0);
      }
    }
    // bias + relu, transpose through LDS: hids[row][h], stride 68
    float* hids = smem + wv * 2176;
#pragma unroll
    for (int tile = 0; tile < 2; ++tile) {
      float bh = b1[tile * 32 + l31];
#pragma unroll
      for (int r = 0; r < 16; ++r) {
        int row = (r & 3) + 8 * (r >> 2) + 4 * half;
        hids[row * 68 + tile * 32 + l31] = fmaxf(acch[tile][r] + bh, 0.f);
      }
    }
    __syncthreads();

    // hidden A-frags: A[m=l31][k=slice*16+half*8+j]
    short8 ahf[4];
#pragma unroll
    for (int s = 0; s < 4; ++s) {
      const float* hr = hids + l31 * 68 + s * 16 + half * 8;
      ahf[s] = cvt8(*(const float4*)hr, *(const float4*)(hr + 4));
    }

    // logits = hidden@W2 + b2: 4 n-tiles x 4 k-slices
    floatx16 accl[4];
#pragma unroll
    for (int tile = 0; tile < 4; ++tile) {
#pragma unroll
      for (int i = 0; i < 16; ++i) accl[tile][i] = 0.f;
#pragma unroll
      for (int s = 0; s < 4; ++s) {
        union { short8 v; unsigned int u[4]; } wf;
#pragma unroll
        for (int jp = 0; jp < 4; ++jp) {
          int k0 = s * 16 + half * 8 + jp * 2;
          float f0 = W2[(size_t)k0 * TT + tile * 32 + l31];
          float f1 = W2[(size_t)(k0 + 1) * TT + tile * 32 + l31];
          wf.u[jp] = pkbf(f0, f1);
        }
        accl[tile] = __builtin_amdgcn_mfma_f32_32x32x16_bf16(
            ahf[s], wf.v, accl[tile], 0, 0, 0);
      }
      float bt = b2[tile * 32 + l31];
#pragma unroll
      for (int i = 0; i < 16; ++i) accl[tile][i] += bt;
    }

    // softmax over t (4 tiles x 32 lanes-in-half), butterfly reduce
    float mrow[16];
#pragma unroll
    for (int r = 0; r < 16; ++r)
      mrow[r] = fmaxf(fmaxf(accl[0][r], accl[1][r]),
                      fmaxf(accl[2][r], accl[3][r]));
#pragma unroll
    for (int msk = 1; msk <= 16; msk <<= 1)
#pragma unroll
      for (int r = 0; r < 16; ++r)
        mrow[r] = fmaxf(mrow[r], __shfl_xor(mrow[r], msk, 64));
    float srow[16];
#pragma unroll
    for (int r = 0; r < 16; ++r) srow[r] = 0.f;
#pragma unroll
    for (int tile = 0; tile < 4; ++tile)
#pragma unroll
      for (int r = 0; r < 16; ++r) {
        float e = __expf(accl[tile][r] - mrow[r]);
        accl[tile][r] = e;
        srow[r] += e;
      }
#pragma unroll
    for (int msk = 1; msk <= 16; msk <<= 1)
#pragma unroll
      for (int r = 0; r < 16; ++r)
        srow[r] += __shfl_xor(srow[r], msk, 64);
#pragma unroll
    for (int r = 0; r < 16; ++r) srow[r] = 1.f / srow[r];

    // store attnB[b][t] fp16 (lanes consecutive t -> coalesced)
#pragma unroll
    for (int tile = 0; tile < 4; ++tile)
#pragma unroll
      for (int r = 0; r < 16; ++r) {
        int row = (r & 3) + 8 * (r >> 2) + 4 * half;
        attnB[(size_t)(b0 + row) * TT + tile * 32 + l31] =
            __float2half(accl[tile][r] * srow[r]);
      }

  } else if (blk < 960) {
    // ---------------- zs branch (MFMA, no LDS), fp16 out --------------------
    const int blk2 = blk - 64;
    const int mb = blk2 >> 5;       // 0..27
    const int ns = blk2 & 31;       // 0..31
    const int m0 = mb * 32;

    short8 af[8];
    const float* mrow = mask + (size_t)(m0 + l31) * II + half * 8;
#pragma unroll
    for (int s = 0; s < 8; ++s)
      af[s] = cvt8(*(const float4*)(mrow + s * 16),
                   *(const float4*)(mrow + s * 16 + 4));
    float th[16];
#pragma unroll
    for (int r = 0; r < 16; ++r)
      th[r] = thr[m0 + (r & 3) + 8 * (r >> 2) + 4 * half];

#pragma unroll
    for (int nb = 0; nb < 2; ++nb) {
      const int n0 = ns * 256 + wv * 64 + nb * 32;
      const float* xrow = x + (size_t)(n0 + l31) * II + half * 8;
      floatx16 acc;
#pragma unroll
      for (int i = 0; i < 16; ++i) acc[i] = 0.f;
#pragma unroll
      for (int s = 0; s < 8; ++s) {
        short8 bf = cvt8(*(const float4*)(xrow + s * 16),
                         *(const float4*)(xrow + s * 16 + 4));
        acc = __builtin_amdgcn_mfma_f32_32x32x16_bf16(af[s], bf, acc, 0, 0, 0);
      }
#pragma unroll
      for (int r = 0; r < 16; ++r) {
        int row = (r & 3) + 8 * (r >> 2) + 4 * half;
        float z = acc[r] - th[r];
        float o = 0.5f * (z / (1.f + fabsf(z)) + 1.f);
        sTh[(size_t)(m0 + row) * BB + n0 + l31] = __float2half(o);
      }
    }

  } else {
    // ---------------- prep branch -------------------------------------------
    float* lps = smem;   // 3072 floats
    const int t0 = (blk - 960) * 2;
    {
      int tl = tid >> 7, l = tid & 127;
      const float* row = lo + ((size_t)(t0 + tl) * 128 + l) * CC;
      float v[CC];
      float m = -1e30f;
#pragma unroll
      for (int c = 0; c < CC; ++c) { v[c] = row[c]; m = fmaxf(m, v[c]); }
      float s = 0.f;
#pragma unroll
      for (int c = 0; c < CC; ++c) { v[c] = __expf(v[c] - m); s += v[c]; }
      float inv = 1.f / s;
      float* o = lps + (tl * 128 + l) * 12;
#pragma unroll
      for (int c = 0; c < CC; ++c) o[c] = v[c] * inv;
      o[10] = 0.f; o[11] = 0.f;
    }
    __syncthreads();

#pragma unroll
    for (int jj = 0; jj < 4; ++jj) {
      int idx = tid + 256 * jj;           // 0..1023 = (tl, s, lane)
      int tl = idx >> 9, rem = idx & 511;
      int s = rem >> 6, ln = rem & 63;
      int hf = ln >> 5, n = ln & 31;
      unsigned int wd[4];
#pragma unroll
      for (int jp = 0; jp < 4; ++jp) {
        int l0 = s * 16 + hf * 8 + jp * 2;
        float f0 = (n < CC) ? lps[(tl * 128 + l0) * 12 + n] : 0.f;
        float f1 = (n < CC) ? lps[(tl * 128 + l0 + 1) * 12 + n] : 0.f;
        wd[jp] = pkbf(f0, f1);
      }
      ((uint4*)lpb)[(size_t)(t0 + tl) * 512 + s * 64 + ln] =
          make_uint4(wd[0], wd[1], wd[2], wd[3]);
    }
  }
}

// ---------------- Kernel 2: main contraction via MFMA -----------------------
// grid (64 bg of 128 b, 16 tg of 8 trees); block 256 = 4 waves.
__global__ __launch_bounds__(256, 4) void main_kernel(
    const __half* __restrict__ sTh, const __half* __restrict__ attnB,
    const unsigned int* __restrict__ lpb, float* __restrict__ partial) {
  __shared__ float red[128 * 10];
  const int bg = blockIdx.x, tg = blockIdx.y;
  const int tid = threadIdx.x;
  const int w = tid >> 6, lane = tid & 63;
  const int half = lane >> 5;
  const int b = bg * 128 + w * 32 + (lane & 31);

  // all 8 tree attn weights for this lane's b: one dwordx4 of fp16
  __half av[8];
  *(uint4*)av = *(const uint4*)(attnB + (size_t)b * TT + tg * 8);

  floatx16 acc;
#pragma unroll
  for (int i = 0; i < 16; ++i) acc[i] = 0.f;

#pragma unroll 1
  for (int it = 0; it < 8; ++it) {
    const int t = tg * 8 + it;
    uint4 bf[8];
    const uint4* lpt = (const uint4*)lpb + (size_t)t * 512 + lane;
#pragma unroll
    for (int s = 0; s < 8; ++s) bf[s] = lpt[s * 64];

    const __half* sp = sTh + (size_t)t * 7 * BB + b;
    float s0 = __half2float(sp[0 * BB]), s1 = __half2float(sp[1 * BB]);
    float s2 = __half2float(sp[2 * BB]), s3 = __half2float(sp[3 * BB]);
    float s4 = __half2float(sp[4 * BB]), s5 = __half2float(sp[5 * BB]);
    float s6 = __half2float(sp[6 * BB]);
    float A = __half2float(av[it]);

    float s0c = 1.f - s0, s1c = 1.f - s1, s2c = 1.f - s2;
    float t0 = s0 * s1, t1 = s0c * s1, t2 = s0 * s1c, t3 = s0c * s1c;
    float pl[8];
    pl[0] = t0 * s2;  pl[1] = t1 * s2;  pl[2] = t2 * s2;  pl[3] = t3 * s2;
    pl[4] = t0 * s2c; pl[5] = t1 * s2c; pl[6] = t2 * s2c; pl[7] = t3 * s2c;
    float sel3 = half ? (1.f - s3) : s3;
    float Af = A * sel3;
    float s4c = 1.f - s4, s5c = 1.f - s5;
    float as6 = Af * s6, as6c = Af * (1.f - s6);
    float u0 = s4 * s5, u1 = s4c * s5, u2 = s4 * s5c, u3 = s4c * s5c;
    float wv[8];
    wv[0] = u0 * as6;  wv[1] = u1 * as6;  wv[2] = u2 * as6;  wv[3] = u3 * as6;
    wv[4] = u0 * as6c; wv[5] = u1 * as6c; wv[6] = u2 * as6c; wv[7] = u3 * as6c;

#pragma unroll
    for (int s = 0; s < 8; ++s) {
      float ws = wv[s];
      union { short8 v; unsigned int u[4]; } a;
#pragma unroll
      for (int jp = 0; jp < 4; ++jp)
        a.u[jp] = pkbf(pl[jp * 2] * ws, pl[jp * 2 + 1] * ws);
      acc = __builtin_amdgcn_mfma_f32_32x32x16_bf16(
          a.v, *(const short8*)&bf[s], acc, 0, 0, 0);
    }
  }

  const int col = lane & 31;
  if (col < CC) {
#pragma unroll
    for (int r = 0; r < 16; ++r) {
      int row = (r & 3) + 8 * (r >> 2) + 4 * half;
      red[(w * 32 + row) * 10 + col] = acc[r];
    }
  }
  __syncthreads();
#pragma unroll
  for (int j = 0; j < 5; ++j) {
    int idx = tid + 256 * j;   // 0..1279
    partial[(size_t)tg * 81920 + (size_t)bg * 1280 + idx] = red[idx];
  }
}

// ---------------- Kernel 3: final reduce over 16 tree-groups ----------------
__global__ __launch_bounds__(256) void reduce_kernel(
    const float* __restrict__ partial, float* __restrict__ out) {
  int idx = blockIdx.x * 256 + threadIdx.x;  // 0..81919
  float s = 0.f;
#pragma unroll
  for (int tg = 0; tg < 16; ++tg) s += partial[(size_t)tg * 81920 + idx];
  out[idx] = s;
}

// ---------------------------------------------------------------------------
extern "C" void kernel_launch(void* const* d_in, const int* in_sizes, int n_in,
                              void* d_out, int out_size, void* d_ws, size_t ws_size,
                              hipStream_t stream) {
  const float* x    = (const float*)d_in[0];
  const float* mask = (const float*)d_in[1];
  const float* thr  = (const float*)d_in[2];
  const float* lo   = (const float*)d_in[3];
  const float* W1   = (const float*)d_in[4];
  const float* b1   = (const float*)d_in[5];
  const float* W2   = (const float*)d_in[6];
  const float* b2   = (const float*)d_in[7];
  float* out = (float*)d_out;
  float* ws  = (float*)d_ws;

  __half*       sTh     = (__half*)(ws + OFF_S);
  __half*       attnB   = (__half*)(ws + OFF_AT);
  unsigned int* LPb     = (unsigned int*)(ws + OFF_LPB);
  float*        partial = ws + OFF_PT;

  phase1_kernel<<<1024, 256, 0, stream>>>(x, mask, thr, lo, W1, b1, W2, b2,
                                          sTh, attnB, LPb);
  main_kernel<<<dim3(64, 16), 256, 0, stream>>>(sTh, attnB, LPb, partial);
  reduce_kernel<<<320, 256, 0, stream>>>(partial, out);
}

// Round 8
// 129.971 us; speedup vs baseline: 1.0982x; 1.0982x over previous
//
#include <hip/hip_runtime.h>
#include <hip/hip_bf16.h>
#include <hip/hip_fp16.h>

// Problem: B=8192, T=128, D=7, I=128, C=10, H=64, L=128
// ws layout (float slots):
//   sTh   fp16 [896][8192]   off 0          (3,670,016)
//   attnB fp16 [8192][128]   off 3,670,016  (524,288)
//   LPb   bf16 B-frags       off 4,194,304  (262,144)
//   partial [16][8192][10]   off 4,456,448  (1,310,720)
// total 5,767,168 floats = 23.1 MB

#define BB 8192
#define TT 128
#define II 128
#define CC 10
#define HH 64

#define OFF_S   0
#define OFF_AT  3670016
#define OFF_LPB 4194304
#define OFF_PT  4456448

typedef __attribute__((ext_vector_type(8))) short short8;
typedef __attribute__((ext_vector_type(16))) float floatx16;

static __device__ inline unsigned int pkbf(float lo, float hi) {
  __hip_bfloat162 h = __float22bfloat162_rn(make_float2(lo, hi));
  unsigned int u;
  __builtin_memcpy(&u, &h, 4);
  return u;
}

static __device__ inline short8 cvt8(float4 a, float4 b) {
  union { short8 v; unsigned int u[4]; } r;
  r.u[0] = pkbf(a.x, a.y);
  r.u[1] = pkbf(a.z, a.w);
  r.u[2] = pkbf(b.x, b.y);
  r.u[3] = pkbf(b.z, b.w);
  return r.v;
}

// ---------------- Phase 1: fused attn (MFMA) + zs (MFMA) + prep -------------
// blocks [0,64): attn | [64,960): zs | [960,1024): prep
// NOTE: __launch_bounds__(256,2) — the attn branch holds ~200 live regs
// (acch+accl+axf+ahf+softmax state); (256,4) capped at 128 and spilled to
// scratch, costing +18us in R7. Do not raise min-waves here.
__global__ __launch_bounds__(256, 2) void phase1_kernel(
    const float* __restrict__ x, const float* __restrict__ mask,
    const float* __restrict__ thr, const float* __restrict__ lo,
    const float* __restrict__ W1, const float* __restrict__ b1,
    const float* __restrict__ W2, const float* __restrict__ b2,
    __half* __restrict__ sTh, __half* __restrict__ attnB,
    unsigned int* __restrict__ lpb) {
  __shared__ float smem[8704];   // 34.8 KB
  const int blk = blockIdx.x;
  const int tid = threadIdx.x;
  const int wv = tid >> 6, lane = tid & 63;
  const int half = lane >> 5, l31 = lane & 31;

  if (blk < 64) {
    // ---------------- attn branch: 128 b-rows/block, 32/wave ----------------
    const int b0 = blk * 128 + wv * 32;

    // x A-frags (rows b0..b0+31, k=0..127)
    short8 axf[8];
    const float* xrow = x + (size_t)(b0 + l31) * II + half * 8;
#pragma unroll
    for (int s = 0; s < 8; ++s)
      axf[s] = cvt8(*(const float4*)(xrow + s * 16),
                    *(const float4*)(xrow + s * 16 + 4));

    // hidden = relu(x@W1 + b1): 2 n-tiles x 8 k-slices
    floatx16 acch[2];
#pragma unroll
    for (int i = 0; i < 16; ++i) { acch[0][i] = 0.f; acch[1][i] = 0.f; }
#pragma unroll
    for (int s = 0; s < 8; ++s) {
#pragma unroll
      for (int tile = 0; tile < 2; ++tile) {
        union { short8 v; unsigned int u[4]; } wf;
#pragma unroll
        for (int jp = 0; jp < 4; ++jp) {
          int k0 = s * 16 + half * 8 + jp * 2;
          float f0 = W1[(size_t)k0 * HH + tile * 32 + l31];
          float f1 = W1[(size_t)(k0 + 1) * HH + tile * 32 + l31];
          wf.u[jp] = pkbf(f0, f1);
        }
        acch[tile] = __builtin_amdgcn_mfma_f32_32x32x16_bf16(
            axf[s], wf.v, acch[tile], 0, 0, 0);
      }
    }
    // bias + relu, transpose through LDS: hids[row][h], stride 68
    float* hids = smem + wv * 2176;
#pragma unroll
    for (int tile = 0; tile < 2; ++tile) {
      float bh = b1[tile * 32 + l31];
#pragma unroll
      for (int r = 0; r < 16; ++r) {
        int row = (r & 3) + 8 * (r >> 2) + 4 * half;
        hids[row * 68 + tile * 32 + l31] = fmaxf(acch[tile][r] + bh, 0.f);
      }
    }
    __syncthreads();

    // hidden A-frags: A[m=l31][k=slice*16+half*8+j]
    short8 ahf[4];
#pragma unroll
    for (int s = 0; s < 4; ++s) {
      const float* hr = hids + l31 * 68 + s * 16 + half * 8;
      ahf[s] = cvt8(*(const float4*)hr, *(const float4*)(hr + 4));
    }

    // logits = hidden@W2 + b2: 4 n-tiles x 4 k-slices
    floatx16 accl[4];
#pragma unroll
    for (int tile = 0; tile < 4; ++tile) {
#pragma unroll
      for (int i = 0; i < 16; ++i) accl[tile][i] = 0.f;
#pragma unroll
      for (int s = 0; s < 4; ++s) {
        union { short8 v; unsigned int u[4]; } wf;
#pragma unroll
        for (int jp = 0; jp < 4; ++jp) {
          int k0 = s * 16 + half * 8 + jp * 2;
          float f0 = W2[(size_t)k0 * TT + tile * 32 + l31];
          float f1 = W2[(size_t)(k0 + 1) * TT + tile * 32 + l31];
          wf.u[jp] = pkbf(f0, f1);
        }
        accl[tile] = __builtin_amdgcn_mfma_f32_32x32x16_bf16(
            ahf[s], wf.v, accl[tile], 0, 0, 0);
      }
      float bt = b2[tile * 32 + l31];
#pragma unroll
      for (int i = 0; i < 16; ++i) accl[tile][i] += bt;
    }

    // softmax over t (4 tiles x 32 lanes-in-half), butterfly reduce
    float mrow[16];
#pragma unroll
    for (int r = 0; r < 16; ++r)
      mrow[r] = fmaxf(fmaxf(accl[0][r], accl[1][r]),
                      fmaxf(accl[2][r], accl[3][r]));
#pragma unroll
    for (int msk = 1; msk <= 16; msk <<= 1)
#pragma unroll
      for (int r = 0; r < 16; ++r)
        mrow[r] = fmaxf(mrow[r], __shfl_xor(mrow[r], msk, 64));
    float srow[16];
#pragma unroll
    for (int r = 0; r < 16; ++r) srow[r] = 0.f;
#pragma unroll
    for (int tile = 0; tile < 4; ++tile)
#pragma unroll
      for (int r = 0; r < 16; ++r) {
        float e = __expf(accl[tile][r] - mrow[r]);
        accl[tile][r] = e;
        srow[r] += e;
      }
#pragma unroll
    for (int msk = 1; msk <= 16; msk <<= 1)
#pragma unroll
      for (int r = 0; r < 16; ++r)
        srow[r] += __shfl_xor(srow[r], msk, 64);
#pragma unroll
    for (int r = 0; r < 16; ++r) srow[r] = 1.f / srow[r];

    // store attnB[b][t] fp16 (lanes consecutive t -> coalesced)
#pragma unroll
    for (int tile = 0; tile < 4; ++tile)
#pragma unroll
      for (int r = 0; r < 16; ++r) {
        int row = (r & 3) + 8 * (r >> 2) + 4 * half;
        attnB[(size_t)(b0 + row) * TT + tile * 32 + l31] =
            __float2half(accl[tile][r] * srow[r]);
      }

  } else if (blk < 960) {
    // ---------------- zs branch (MFMA, no LDS), fp16 out --------------------
    const int blk2 = blk - 64;
    const int mb = blk2 >> 5;       // 0..27
    const int ns = blk2 & 31;       // 0..31
    const int m0 = mb * 32;

    short8 af[8];
    const float* mrow = mask + (size_t)(m0 + l31) * II + half * 8;
#pragma unroll
    for (int s = 0; s < 8; ++s)
      af[s] = cvt8(*(const float4*)(mrow + s * 16),
                   *(const float4*)(mrow + s * 16 + 4));
    float th[16];
#pragma unroll
    for (int r = 0; r < 16; ++r)
      th[r] = thr[m0 + (r & 3) + 8 * (r >> 2) + 4 * half];

#pragma unroll
    for (int nb = 0; nb < 2; ++nb) {
      const int n0 = ns * 256 + wv * 64 + nb * 32;
      const float* xrow = x + (size_t)(n0 + l31) * II + half * 8;
      floatx16 acc;
#pragma unroll
      for (int i = 0; i < 16; ++i) acc[i] = 0.f;
#pragma unroll
      for (int s = 0; s < 8; ++s) {
        short8 bf = cvt8(*(const float4*)(xrow + s * 16),
                         *(const float4*)(xrow + s * 16 + 4));
        acc = __builtin_amdgcn_mfma_f32_32x32x16_bf16(af[s], bf, acc, 0, 0, 0);
      }
#pragma unroll
      for (int r = 0; r < 16; ++r) {
        int row = (r & 3) + 8 * (r >> 2) + 4 * half;
        float z = acc[r] - th[r];
        float o = 0.5f * (z / (1.f + fabsf(z)) + 1.f);
        sTh[(size_t)(m0 + row) * BB + n0 + l31] = __float2half(o);
      }
    }

  } else {
    // ---------------- prep branch -------------------------------------------
    float* lps = smem;   // 3072 floats
    const int t0 = (blk - 960) * 2;
    {
      int tl = tid >> 7, l = tid & 127;
      const float* row = lo + ((size_t)(t0 + tl) * 128 + l) * CC;
      float v[CC];
      float m = -1e30f;
#pragma unroll
      for (int c = 0; c < CC; ++c) { v[c] = row[c]; m = fmaxf(m, v[c]); }
      float s = 0.f;
#pragma unroll
      for (int c = 0; c < CC; ++c) { v[c] = __expf(v[c] - m); s += v[c]; }
      float inv = 1.f / s;
      float* o = lps + (tl * 128 + l) * 12;
#pragma unroll
      for (int c = 0; c < CC; ++c) o[c] = v[c] * inv;
      o[10] = 0.f; o[11] = 0.f;
    }
    __syncthreads();

#pragma unroll
    for (int jj = 0; jj < 4; ++jj) {
      int idx = tid + 256 * jj;           // 0..1023 = (tl, s, lane)
      int tl = idx >> 9, rem = idx & 511;
      int s = rem >> 6, ln = rem & 63;
      int hf = ln >> 5, n = ln & 31;
      unsigned int wd[4];
#pragma unroll
      for (int jp = 0; jp < 4; ++jp) {
        int l0 = s * 16 + hf * 8 + jp * 2;
        float f0 = (n < CC) ? lps[(tl * 128 + l0) * 12 + n] : 0.f;
        float f1 = (n < CC) ? lps[(tl * 128 + l0 + 1) * 12 + n] : 0.f;
        wd[jp] = pkbf(f0, f1);
      }
      ((uint4*)lpb)[(size_t)(t0 + tl) * 512 + s * 64 + ln] =
          make_uint4(wd[0], wd[1], wd[2], wd[3]);
    }
  }
}

// ---------------- Kernel 2: main contraction via MFMA -----------------------
// grid (64 bg of 128 b, 16 tg of 8 trees); block 256 = 4 waves.
__global__ __launch_bounds__(256, 4) void main_kernel(
    const __half* __restrict__ sTh, const __half* __restrict__ attnB,
    const unsigned int* __restrict__ lpb, float* __restrict__ partial) {
  __shared__ float red[128 * 10];
  const int bg = blockIdx.x, tg = blockIdx.y;
  const int tid = threadIdx.x;
  const int w = tid >> 6, lane = tid & 63;
  const int half = lane >> 5;
  const int b = bg * 128 + w * 32 + (lane & 31);

  // all 8 tree attn weights for this lane's b: one dwordx4 of fp16
  __half av[8];
  *(uint4*)av = *(const uint4*)(attnB + (size_t)b * TT + tg * 8);

  floatx16 acc;
#pragma unroll
  for (int i = 0; i < 16; ++i) acc[i] = 0.f;

#pragma unroll 1
  for (int it = 0; it < 8; ++it) {
    const int t = tg * 8 + it;
    uint4 bf[8];
    const uint4* lpt = (const uint4*)lpb + (size_t)t * 512 + lane;
#pragma unroll
    for (int s = 0; s < 8; ++s) bf[s] = lpt[s * 64];

    const __half* sp = sTh + (size_t)t * 7 * BB + b;
    float s0 = __half2float(sp[0 * BB]), s1 = __half2float(sp[1 * BB]);
    float s2 = __half2float(sp[2 * BB]), s3 = __half2float(sp[3 * BB]);
    float s4 = __half2float(sp[4 * BB]), s5 = __half2float(sp[5 * BB]);
    float s6 = __half2float(sp[6 * BB]);
    float A = __half2float(av[it]);

    float s0c = 1.f - s0, s1c = 1.f - s1, s2c = 1.f - s2;
    float t0 = s0 * s1, t1 = s0c * s1, t2 = s0 * s1c, t3 = s0c * s1c;
    float pl[8];
    pl[0] = t0 * s2;  pl[1] = t1 * s2;  pl[2] = t2 * s2;  pl[3] = t3 * s2;
    pl[4] = t0 * s2c; pl[5] = t1 * s2c; pl[6] = t2 * s2c; pl[7] = t3 * s2c;
    float sel3 = half ? (1.f - s3) : s3;
    float Af = A * sel3;
    float s4c = 1.f - s4, s5c = 1.f - s5;
    float as6 = Af * s6, as6c = Af * (1.f - s6);
    float u0 = s4 * s5, u1 = s4c * s5, u2 = s4 * s5c, u3 = s4c * s5c;
    float wv[8];
    wv[0] = u0 * as6;  wv[1] = u1 * as6;  wv[2] = u2 * as6;  wv[3] = u3 * as6;
    wv[4] = u0 * as6c; wv[5] = u1 * as6c; wv[6] = u2 * as6c; wv[7] = u3 * as6c;

#pragma unroll
    for (int s = 0; s < 8; ++s) {
      float ws = wv[s];
      union { short8 v; unsigned int u[4]; } a;
#pragma unroll
      for (int jp = 0; jp < 4; ++jp)
        a.u[jp] = pkbf(pl[jp * 2] * ws, pl[jp * 2 + 1] * ws);
      acc = __builtin_amdgcn_mfma_f32_32x32x16_bf16(
          a.v, *(const short8*)&bf[s], acc, 0, 0, 0);
    }
  }

  const int col = lane & 31;
  if (col < CC) {
#pragma unroll
    for (int r = 0; r < 16; ++r) {
      int row = (r & 3) + 8 * (r >> 2) + 4 * half;
      red[(w * 32 + row) * 10 + col] = acc[r];
    }
  }
  __syncthreads();
#pragma unroll
  for (int j = 0; j < 5; ++j) {
    int idx = tid + 256 * j;   // 0..1279
    partial[(size_t)tg * 81920 + (size_t)bg * 1280 + idx] = red[idx];
  }
}

// ---------------- Kernel 3: final reduce over 16 tree-groups ----------------
__global__ __launch_bounds__(256) void reduce_kernel(
    const float* __restrict__ partial, float* __restrict__ out) {
  int idx = blockIdx.x * 256 + threadIdx.x;  // 0..81919
  float s = 0.f;
#pragma unroll
  for (int tg = 0; tg < 16; ++tg) s += partial[(size_t)tg * 81920 + idx];
  out[idx] = s;
}

// ---------------------------------------------------------------------------
extern "C" void kernel_launch(void* const* d_in, const int* in_sizes, int n_in,
                              void* d_out, int out_size, void* d_ws, size_t ws_size,
                              hipStream_t stream) {
  const float* x    = (const float*)d_in[0];
  const float* mask = (const float*)d_in[1];
  const float* thr  = (const float*)d_in[2];
  const float* lo   = (const float*)d_in[3];
  const float* W1   = (const float*)d_in[4];
  const float* b1   = (const float*)d_in[5];
  const float* W2   = (const float*)d_in[6];
  const float* b2   = (const float*)d_in[7];
  float* out = (float*)d_out;
  float* ws  = (float*)d_ws;

  __half*       sTh     = (__half*)(ws + OFF_S);
  __half*       attnB   = (__half*)(ws + OFF_AT);
  unsigned int* LPb     = (unsigned int*)(ws + OFF_LPB);
  float*        partial = ws + OFF_PT;

  phase1_kernel<<<1024, 256, 0, stream>>>(x, mask, thr, lo, W1, b1, W2, b2,
                                          sTh, attnB, LPb);
  main_kernel<<<dim3(64, 16), 256, 0, stream>>>(sTh, attnB, LPb, partial);
  reduce_kernel<<<320, 256, 0, stream>>>(partial, out);
}

// Round 9
// 124.358 us; speedup vs baseline: 1.1478x; 1.0451x over previous
//
#include <hip/hip_runtime.h>
#include <hip/hip_bf16.h>
#include <hip/hip_fp16.h>

// Problem: B=8192, T=128, D=7, I=128, C=10, H=64, L=128
// ws layout (float slots):
//   sPack fp16 [128][8192][8]  off 0          (4,194,304)  d0..6 = s, d7 = attn
//   LPb   fp16 B-frags         off 4,194,304  (262,144)
//   partial [16][8192][10]     off 4,456,448  (1,310,720)
// total 5,767,168 floats = 23.1 MB

#define BB 8192
#define TT 128
#define II 128
#define CC 10
#define HH 64

#define OFF_S   0
#define OFF_LPB 4194304
#define OFF_PT  4456448

typedef __attribute__((ext_vector_type(8))) short short8;
typedef __attribute__((ext_vector_type(16))) float floatx16;

static __device__ inline unsigned int pkbf(float lo, float hi) {
  __hip_bfloat162 h = __float22bfloat162_rn(make_float2(lo, hi));
  unsigned int u;
  __builtin_memcpy(&u, &h, 4);
  return u;
}

static __device__ inline unsigned int pkh(float lo, float hi) {
  __half2 h = __float22half2_rn(make_float2(lo, hi));
  unsigned int u;
  __builtin_memcpy(&u, &h, 4);
  return u;
}

static __device__ inline short8 cvt8(float4 a, float4 b) {
  union { short8 v; unsigned int u[4]; } r;
  r.u[0] = pkbf(a.x, a.y);
  r.u[1] = pkbf(a.z, a.w);
  r.u[2] = pkbf(b.x, b.y);
  r.u[3] = pkbf(b.z, b.w);
  return r.v;
}

// ---------------- Phase 1: fused attn (MFMA) + zs (MFMA) + prep -------------
// blocks [0,64): attn | [64,960): zs | [960,1024): prep
// NOTE: __launch_bounds__(256,2) — the attn branch holds ~200 live regs;
// (256,4) capped at 128 and spilled to scratch, costing +18us in R7.
__global__ __launch_bounds__(256, 2) void phase1_kernel(
    const float* __restrict__ x, const float* __restrict__ mask,
    const float* __restrict__ thr, const float* __restrict__ lo,
    const float* __restrict__ W1, const float* __restrict__ b1,
    const float* __restrict__ W2, const float* __restrict__ b2,
    __half* __restrict__ sPack, unsigned int* __restrict__ lpb) {
  __shared__ float smem[8704];   // 34.8 KB
  const int blk = blockIdx.x;
  const int tid = threadIdx.x;
  const int wv = tid >> 6, lane = tid & 63;
  const int half = lane >> 5, l31 = lane & 31;

  if (blk < 64) {
    // ---------------- attn branch: 128 b-rows/block, 32/wave ----------------
    const int b0 = blk * 128 + wv * 32;

    short8 axf[8];
    const float* xrow = x + (size_t)(b0 + l31) * II + half * 8;
#pragma unroll
    for (int s = 0; s < 8; ++s)
      axf[s] = cvt8(*(const float4*)(xrow + s * 16),
                    *(const float4*)(xrow + s * 16 + 4));

    // hidden = relu(x@W1 + b1): 2 n-tiles x 8 k-slices
    floatx16 acch[2];
#pragma unroll
    for (int i = 0; i < 16; ++i) { acch[0][i] = 0.f; acch[1][i] = 0.f; }
#pragma unroll
    for (int s = 0; s < 8; ++s) {
#pragma unroll
      for (int tile = 0; tile < 2; ++tile) {
        union { short8 v; unsigned int u[4]; } wf;
#pragma unroll
        for (int jp = 0; jp < 4; ++jp) {
          int k0 = s * 16 + half * 8 + jp * 2;
          float f0 = W1[(size_t)k0 * HH + tile * 32 + l31];
          float f1 = W1[(size_t)(k0 + 1) * HH + tile * 32 + l31];
          wf.u[jp] = pkbf(f0, f1);
        }
        acch[tile] = __builtin_amdgcn_mfma_f32_32x32x16_bf16(
            axf[s], wf.v, acch[tile], 0, 0, 0);
      }
    }
    float* hids = smem + wv * 2176;
#pragma unroll
    for (int tile = 0; tile < 2; ++tile) {
      float bh = b1[tile * 32 + l31];
#pragma unroll
      for (int r = 0; r < 16; ++r) {
        int row = (r & 3) + 8 * (r >> 2) + 4 * half;
        hids[row * 68 + tile * 32 + l31] = fmaxf(acch[tile][r] + bh, 0.f);
      }
    }
    __syncthreads();

    short8 ahf[4];
#pragma unroll
    for (int s = 0; s < 4; ++s) {
      const float* hr = hids + l31 * 68 + s * 16 + half * 8;
      ahf[s] = cvt8(*(const float4*)hr, *(const float4*)(hr + 4));
    }

    // logits = hidden@W2 + b2: 4 n-tiles x 4 k-slices
    floatx16 accl[4];
#pragma unroll
    for (int tile = 0; tile < 4; ++tile) {
#pragma unroll
      for (int i = 0; i < 16; ++i) accl[tile][i] = 0.f;
#pragma unroll
      for (int s = 0; s < 4; ++s) {
        union { short8 v; unsigned int u[4]; } wf;
#pragma unroll
        for (int jp = 0; jp < 4; ++jp) {
          int k0 = s * 16 + half * 8 + jp * 2;
          float f0 = W2[(size_t)k0 * TT + tile * 32 + l31];
          float f1 = W2[(size_t)(k0 + 1) * TT + tile * 32 + l31];
          wf.u[jp] = pkbf(f0, f1);
        }
        accl[tile] = __builtin_amdgcn_mfma_f32_32x32x16_bf16(
            ahf[s], wf.v, accl[tile], 0, 0, 0);
      }
      float bt = b2[tile * 32 + l31];
#pragma unroll
      for (int i = 0; i < 16; ++i) accl[tile][i] += bt;
    }

    // softmax over t, butterfly reduce
    float mrow[16];
#pragma unroll
    for (int r = 0; r < 16; ++r)
      mrow[r] = fmaxf(fmaxf(accl[0][r], accl[1][r]),
                      fmaxf(accl[2][r], accl[3][r]));
#pragma unroll
    for (int msk = 1; msk <= 16; msk <<= 1)
#pragma unroll
      for (int r = 0; r < 16; ++r)
        mrow[r] = fmaxf(mrow[r], __shfl_xor(mrow[r], msk, 64));
    float srow[16];
#pragma unroll
    for (int r = 0; r < 16; ++r) srow[r] = 0.f;
#pragma unroll
    for (int tile = 0; tile < 4; ++tile)
#pragma unroll
      for (int r = 0; r < 16; ++r) {
        float e = __expf(accl[tile][r] - mrow[r]);
        accl[tile][r] = e;
        srow[r] += e;
      }
#pragma unroll
    for (int msk = 1; msk <= 16; msk <<= 1)
#pragma unroll
      for (int r = 0; r < 16; ++r)
        srow[r] += __shfl_xor(srow[r], msk, 64);
#pragma unroll
    for (int r = 0; r < 16; ++r) srow[r] = 1.f / srow[r];

    // store attn into sPack slot 7: t = tile*32+l31, b = b0+row
#pragma unroll
    for (int tile = 0; tile < 4; ++tile)
#pragma unroll
      for (int r = 0; r < 16; ++r) {
        int row = (r & 3) + 8 * (r >> 2) + 4 * half;
        sPack[((size_t)(tile * 32 + l31) * BB + (b0 + row)) * 8 + 7] =
            __float2half(accl[tile][r] * srow[r]);
      }

  } else if (blk < 960) {
    // ---------------- zs branch (MFMA, no LDS) -> sPack slots 0..6 ----------
    const int blk2 = blk - 64;
    const int mb = blk2 >> 5;       // 0..27
    const int ns = blk2 & 31;       // 0..31
    const int m0 = mb * 32;

    short8 af[8];
    const float* mrow = mask + (size_t)(m0 + l31) * II + half * 8;
#pragma unroll
    for (int s = 0; s < 8; ++s)
      af[s] = cvt8(*(const float4*)(mrow + s * 16),
                   *(const float4*)(mrow + s * 16 + 4));
    float th[16];
#pragma unroll
    for (int r = 0; r < 16; ++r)
      th[r] = thr[m0 + (r & 3) + 8 * (r >> 2) + 4 * half];

#pragma unroll
    for (int nb = 0; nb < 2; ++nb) {
      const int n0 = ns * 256 + wv * 64 + nb * 32;
      const float* xrow = x + (size_t)(n0 + l31) * II + half * 8;
      floatx16 acc;
#pragma unroll
      for (int i = 0; i < 16; ++i) acc[i] = 0.f;
#pragma unroll
      for (int s = 0; s < 8; ++s) {
        short8 bf = cvt8(*(const float4*)(xrow + s * 16),
                         *(const float4*)(xrow + s * 16 + 4));
        acc = __builtin_amdgcn_mfma_f32_32x32x16_bf16(af[s], bf, acc, 0, 0, 0);
      }
      const int b = n0 + l31;
#pragma unroll
      for (int r = 0; r < 16; ++r) {
        int row = (r & 3) + 8 * (r >> 2) + 4 * half;
        int m = m0 + row;                    // td index
        int t = (m * 9363) >> 16;            // m / 7 (valid for m < 896)
        int d = m - t * 7;
        float z = acc[r] - th[r];
        float o = 0.5f * (z / (1.f + fabsf(z)) + 1.f);
        sPack[((size_t)t * BB + b) * 8 + d] = __float2half(o);
      }
    }

  } else {
    // ---------------- prep branch: leaf softmax -> fp16 B-frags -------------
    float* lps = smem;   // 3072 floats
    const int t0 = (blk - 960) * 2;
    {
      int tl = tid >> 7, l = tid & 127;
      const float* row = lo + ((size_t)(t0 + tl) * 128 + l) * CC;
      float v[CC];
      float m = -1e30f;
#pragma unroll
      for (int c = 0; c < CC; ++c) { v[c] = row[c]; m = fmaxf(m, v[c]); }
      float s = 0.f;
#pragma unroll
      for (int c = 0; c < CC; ++c) { v[c] = __expf(v[c] - m); s += v[c]; }
      float inv = 1.f / s;
      float* o = lps + (tl * 128 + l) * 12;
#pragma unroll
      for (int c = 0; c < CC; ++c) o[c] = v[c] * inv;
      o[10] = 0.f; o[11] = 0.f;
    }
    __syncthreads();

#pragma unroll
    for (int jj = 0; jj < 4; ++jj) {
      int idx = tid + 256 * jj;           // 0..1023 = (tl, s, lane)
      int tl = idx >> 9, rem = idx & 511;
      int s = rem >> 6, ln = rem & 63;
      int hf = ln >> 5, n = ln & 31;
      unsigned int wd[4];
#pragma unroll
      for (int jp = 0; jp < 4; ++jp) {
        int l0 = s * 16 + hf * 8 + jp * 2;
        float f0 = (n < CC) ? lps[(tl * 128 + l0) * 12 + n] : 0.f;
        float f1 = (n < CC) ? lps[(tl * 128 + l0 + 1) * 12 + n] : 0.f;
        wd[jp] = pkh(f0, f1);               // fp16 now
      }
      ((uint4*)lpb)[(size_t)(t0 + tl) * 512 + s * 64 + ln] =
          make_uint4(wd[0], wd[1], wd[2], wd[3]);
    }
  }
}

// ---------------- Kernel 2: main contraction via MFMA (fp16) ----------------
// grid (64 bg of 128 b, 16 tg of 8 trees); block 256 = 4 waves.
// Per t-iter: ONE coalesced dwordx4 gives s0..s6+A (sv double-buffered);
// bf loads at iter top hide under the VALU block. a-frags via __hmul2.
__global__ __launch_bounds__(256, 4) void main_kernel(
    const __half* __restrict__ sPack, const unsigned int* __restrict__ lpb,
    float* __restrict__ partial) {
  __shared__ float red[128 * 10];
  const int bg = blockIdx.x, tg = blockIdx.y;
  const int tid = threadIdx.x;
  const int w = tid >> 6, lane = tid & 63;
  const int half = lane >> 5;
  const int b = bg * 128 + w * 32 + (lane & 31);
  const uint4* spk = (const uint4*)sPack;

  floatx16 acc;
#pragma unroll
  for (int i = 0; i < 16; ++i) acc[i] = 0.f;

  uint4 sv[2];
  sv[0] = spk[(size_t)(tg * 8) * BB + b];

#pragma unroll
  for (int it = 0; it < 8; ++it) {
    const int cur = it & 1;
    const int t = tg * 8 + it;
    // bf loads (L2-hot, hidden under the VALU block below)
    uint4 bf[8];
    const uint4* lpt = (const uint4*)lpb + (size_t)t * 512 + lane;
#pragma unroll
    for (int s = 0; s < 8; ++s) bf[s] = lpt[s * 64];
    // prefetch next iteration's s-vector
    if (it < 7) sv[cur ^ 1] = spk[(size_t)(t + 1) * BB + b];

    const __half* sh = (const __half*)&sv[cur];
    float s0 = __half2float(sh[0]), s1 = __half2float(sh[1]);
    float s2 = __half2float(sh[2]), s3 = __half2float(sh[3]);
    float s4 = __half2float(sh[4]), s5 = __half2float(sh[5]);
    float s6 = __half2float(sh[6]), A  = __half2float(sh[7]);

    float s0c = 1.f - s0, s1c = 1.f - s1, s2c = 1.f - s2;
    float t0 = s0 * s1, t1 = s0c * s1, t2 = s0 * s1c, t3 = s0c * s1c;
    float pl[8];
    pl[0] = t0 * s2;  pl[1] = t1 * s2;  pl[2] = t2 * s2;  pl[3] = t3 * s2;
    pl[4] = t0 * s2c; pl[5] = t1 * s2c; pl[6] = t2 * s2c; pl[7] = t3 * s2c;
    float sel3 = half ? (1.f - s3) : s3;
    float Af = A * sel3;
    float s4c = 1.f - s4, s5c = 1.f - s5;
    float as6 = Af * s6, as6c = Af * (1.f - s6);
    float u0 = s4 * s5, u1 = s4c * s5, u2 = s4 * s5c, u3 = s4c * s5c;
    float wv[8];
    wv[0] = u0 * as6;  wv[1] = u1 * as6;  wv[2] = u2 * as6;  wv[3] = u3 * as6;
    wv[4] = u0 * as6c; wv[5] = u1 * as6c; wv[6] = u2 * as6c; wv[7] = u3 * as6c;

    __half2 pl2[4];
#pragma unroll
    for (int jp = 0; jp < 4; ++jp)
      pl2[jp] = __float22half2_rn(make_float2(pl[jp * 2], pl[jp * 2 + 1]));

#pragma unroll
    for (int s = 0; s < 8; ++s) {
      __half2 w2 = __half2half2(__float2half(wv[s]));
      union { short8 v; __half2 h[4]; } a;
#pragma unroll
      for (int jp = 0; jp < 4; ++jp) a.h[jp] = __hmul2(pl2[jp], w2);
      acc = __builtin_amdgcn_mfma_f32_32x32x16_f16(
          a.v, *(const short8*)&bf[s], acc, 0, 0, 0);
    }
  }

  const int col = lane & 31;
  if (col < CC) {
#pragma unroll
    for (int r = 0; r < 16; ++r) {
      int row = (r & 3) + 8 * (r >> 2) + 4 * half;
      red[(w * 32 + row) * 10 + col] = acc[r];
    }
  }
  __syncthreads();
#pragma unroll
  for (int j = 0; j < 5; ++j) {
    int idx = tid + 256 * j;   // 0..1279
    partial[(size_t)tg * 81920 + (size_t)bg * 1280 + idx] = red[idx];
  }
}

// ---------------- Kernel 3: final reduce over 16 tree-groups ----------------
__global__ __launch_bounds__(256) void reduce_kernel(
    const float* __restrict__ partial, float* __restrict__ out) {
  int idx = blockIdx.x * 256 + threadIdx.x;  // 0..81919
  float s = 0.f;
#pragma unroll
  for (int tg = 0; tg < 16; ++tg) s += partial[(size_t)tg * 81920 + idx];
  out[idx] = s;
}

// ---------------------------------------------------------------------------
extern "C" void kernel_launch(void* const* d_in, const int* in_sizes, int n_in,
                              void* d_out, int out_size, void* d_ws, size_t ws_size,
                              hipStream_t stream) {
  const float* x    = (const float*)d_in[0];
  const float* mask = (const float*)d_in[1];
  const float* thr  = (const float*)d_in[2];
  const float* lo   = (const float*)d_in[3];
  const float* W1   = (const float*)d_in[4];
  const float* b1   = (const float*)d_in[5];
  const float* W2   = (const float*)d_in[6];
  const float* b2   = (const float*)d_in[7];
  float* out = (float*)d_out;
  float* ws  = (float*)d_ws;

  __half*       sPack   = (__half*)(ws + OFF_S);
  unsigned int* LPb     = (unsigned int*)(ws + OFF_LPB);
  float*        partial = ws + OFF_PT;

  phase1_kernel<<<1024, 256, 0, stream>>>(x, mask, thr, lo, W1, b1, W2, b2,
                                          sPack, LPb);
  main_kernel<<<dim3(64, 16), 256, 0, stream>>>(sPack, LPb, partial);
  reduce_kernel<<<320, 256, 0, stream>>>(partial, out);
}

// Round 10
// 118.259 us; speedup vs baseline: 1.2070x; 1.0516x over previous
//
#include <hip/hip_runtime.h>
#include <hip/hip_bf16.h>
#include <hip/hip_fp16.h>

// Problem: B=8192, T=128, D=7, I=128, C=10, H=64, L=128
// ws layout (float slots):
//   sTh   fp16 [896][8192]     off 0          (3,670,016)
//   attnB fp16 [8192][128]     off 3,670,016  (524,288)
//   sPack fp16 [128][8192][8]  off 4,194,304  (4,194,304)  d0..6 = s, d7 = 0
//   LPb   fp16 B-frags         off 8,388,608  (262,144)
//   partial [16][8192][10]     off 8,650,752  (1,310,720)
// total 9,961,472 floats = 39.85 MB

#define BB 8192
#define TT 128
#define II 128
#define CC 10
#define HH 64

#define OFF_STH 0
#define OFF_AT  3670016
#define OFF_SP  4194304
#define OFF_LPB 8388608
#define OFF_PT  8650752

typedef __attribute__((ext_vector_type(8))) short short8;
typedef __attribute__((ext_vector_type(16))) float floatx16;

static __device__ inline unsigned int pkbf(float lo, float hi) {
  __hip_bfloat162 h = __float22bfloat162_rn(make_float2(lo, hi));
  unsigned int u;
  __builtin_memcpy(&u, &h, 4);
  return u;
}

static __device__ inline unsigned int pkh(float lo, float hi) {
  __half2 h = __float22half2_rn(make_float2(lo, hi));
  unsigned int u;
  __builtin_memcpy(&u, &h, 4);
  return u;
}

static __device__ inline short8 cvt8(float4 a, float4 b) {
  union { short8 v; unsigned int u[4]; } r;
  r.u[0] = pkbf(a.x, a.y);
  r.u[1] = pkbf(a.z, a.w);
  r.u[2] = pkbf(b.x, b.y);
  r.u[3] = pkbf(b.z, b.w);
  return r.v;
}

// ---------------- Phase 1: fused attn (MFMA) + zs (MFMA) + prep -------------
// blocks [0,64): attn | [64,960): zs | [960,1024): prep
// NOTE: __launch_bounds__(256,2) — attn branch holds ~200 live regs; (256,4)
// capped at 128 and spilled (+18us in R7). All stores COALESCED (R9's
// sPack scatter-store cost 2x write amplification; transpose moved to repack).
__global__ __launch_bounds__(256, 2) void phase1_kernel(
    const float* __restrict__ x, const float* __restrict__ mask,
    const float* __restrict__ thr, const float* __restrict__ lo,
    const float* __restrict__ W1, const float* __restrict__ b1,
    const float* __restrict__ W2, const float* __restrict__ b2,
    __half* __restrict__ sTh, __half* __restrict__ attnB,
    unsigned int* __restrict__ lpb) {
  __shared__ float smem[8704];   // 34.8 KB
  const int blk = blockIdx.x;
  const int tid = threadIdx.x;
  const int wv = tid >> 6, lane = tid & 63;
  const int half = lane >> 5, l31 = lane & 31;

  if (blk < 64) {
    // ---------------- attn branch: 128 b-rows/block, 32/wave ----------------
    const int b0 = blk * 128 + wv * 32;

    short8 axf[8];
    const float* xrow = x + (size_t)(b0 + l31) * II + half * 8;
#pragma unroll
    for (int s = 0; s < 8; ++s)
      axf[s] = cvt8(*(const float4*)(xrow + s * 16),
                    *(const float4*)(xrow + s * 16 + 4));

    // hidden = relu(x@W1 + b1): 2 n-tiles x 8 k-slices
    floatx16 acch[2];
#pragma unroll
    for (int i = 0; i < 16; ++i) { acch[0][i] = 0.f; acch[1][i] = 0.f; }
#pragma unroll
    for (int s = 0; s < 8; ++s) {
#pragma unroll
      for (int tile = 0; tile < 2; ++tile) {
        union { short8 v; unsigned int u[4]; } wf;
#pragma unroll
        for (int jp = 0; jp < 4; ++jp) {
          int k0 = s * 16 + half * 8 + jp * 2;
          float f0 = W1[(size_t)k0 * HH + tile * 32 + l31];
          float f1 = W1[(size_t)(k0 + 1) * HH + tile * 32 + l31];
          wf.u[jp] = pkbf(f0, f1);
        }
        acch[tile] = __builtin_amdgcn_mfma_f32_32x32x16_bf16(
            axf[s], wf.v, acch[tile], 0, 0, 0);
      }
    }
    float* hids = smem + wv * 2176;
#pragma unroll
    for (int tile = 0; tile < 2; ++tile) {
      float bh = b1[tile * 32 + l31];
#pragma unroll
      for (int r = 0; r < 16; ++r) {
        int row = (r & 3) + 8 * (r >> 2) + 4 * half;
        hids[row * 68 + tile * 32 + l31] = fmaxf(acch[tile][r] + bh, 0.f);
      }
    }
    __syncthreads();

    short8 ahf[4];
#pragma unroll
    for (int s = 0; s < 4; ++s) {
      const float* hr = hids + l31 * 68 + s * 16 + half * 8;
      ahf[s] = cvt8(*(const float4*)hr, *(const float4*)(hr + 4));
    }

    // logits = hidden@W2 + b2: 4 n-tiles x 4 k-slices
    floatx16 accl[4];
#pragma unroll
    for (int tile = 0; tile < 4; ++tile) {
#pragma unroll
      for (int i = 0; i < 16; ++i) accl[tile][i] = 0.f;
#pragma unroll
      for (int s = 0; s < 4; ++s) {
        union { short8 v; unsigned int u[4]; } wf;
#pragma unroll
        for (int jp = 0; jp < 4; ++jp) {
          int k0 = s * 16 + half * 8 + jp * 2;
          float f0 = W2[(size_t)k0 * TT + tile * 32 + l31];
          float f1 = W2[(size_t)(k0 + 1) * TT + tile * 32 + l31];
          wf.u[jp] = pkbf(f0, f1);
        }
        accl[tile] = __builtin_amdgcn_mfma_f32_32x32x16_bf16(
            ahf[s], wf.v, accl[tile], 0, 0, 0);
      }
      float bt = b2[tile * 32 + l31];
#pragma unroll
      for (int i = 0; i < 16; ++i) accl[tile][i] += bt;
    }

    // softmax over t, butterfly reduce
    float mrow[16];
#pragma unroll
    for (int r = 0; r < 16; ++r)
      mrow[r] = fmaxf(fmaxf(accl[0][r], accl[1][r]),
                      fmaxf(accl[2][r], accl[3][r]));
#pragma unroll
    for (int msk = 1; msk <= 16; msk <<= 1)
#pragma unroll
      for (int r = 0; r < 16; ++r)
        mrow[r] = fmaxf(mrow[r], __shfl_xor(mrow[r], msk, 64));
    float srow[16];
#pragma unroll
    for (int r = 0; r < 16; ++r) srow[r] = 0.f;
#pragma unroll
    for (int tile = 0; tile < 4; ++tile)
#pragma unroll
      for (int r = 0; r < 16; ++r) {
        float e = __expf(accl[tile][r] - mrow[r]);
        accl[tile][r] = e;
        srow[r] += e;
      }
#pragma unroll
    for (int msk = 1; msk <= 16; msk <<= 1)
#pragma unroll
      for (int r = 0; r < 16; ++r)
        srow[r] += __shfl_xor(srow[r], msk, 64);
#pragma unroll
    for (int r = 0; r < 16; ++r) srow[r] = 1.f / srow[r];

    // store attnB[b][t] fp16 (lanes consecutive t -> coalesced)
#pragma unroll
    for (int tile = 0; tile < 4; ++tile)
#pragma unroll
      for (int r = 0; r < 16; ++r) {
        int row = (r & 3) + 8 * (r >> 2) + 4 * half;
        attnB[(size_t)(b0 + row) * TT + tile * 32 + l31] =
            __float2half(accl[tile][r] * srow[r]);
      }

  } else if (blk < 960) {
    // ---------------- zs branch (MFMA, no LDS) -> sTh[td][b] coalesced ------
    const int blk2 = blk - 64;
    const int mb = blk2 >> 5;       // 0..27
    const int ns = blk2 & 31;       // 0..31
    const int m0 = mb * 32;

    short8 af[8];
    const float* mrow = mask + (size_t)(m0 + l31) * II + half * 8;
#pragma unroll
    for (int s = 0; s < 8; ++s)
      af[s] = cvt8(*(const float4*)(mrow + s * 16),
                   *(const float4*)(mrow + s * 16 + 4));
    float th[16];
#pragma unroll
    for (int r = 0; r < 16; ++r)
      th[r] = thr[m0 + (r & 3) + 8 * (r >> 2) + 4 * half];

#pragma unroll
    for (int nb = 0; nb < 2; ++nb) {
      const int n0 = ns * 256 + wv * 64 + nb * 32;
      const float* xrow = x + (size_t)(n0 + l31) * II + half * 8;
      floatx16 acc;
#pragma unroll
      for (int i = 0; i < 16; ++i) acc[i] = 0.f;
#pragma unroll
      for (int s = 0; s < 8; ++s) {
        short8 bf = cvt8(*(const float4*)(xrow + s * 16),
                         *(const float4*)(xrow + s * 16 + 4));
        acc = __builtin_amdgcn_mfma_f32_32x32x16_bf16(af[s], bf, acc, 0, 0, 0);
      }
#pragma unroll
      for (int r = 0; r < 16; ++r) {
        int row = (r & 3) + 8 * (r >> 2) + 4 * half;
        float z = acc[r] - th[r];
        float o = 0.5f * (z / (1.f + fabsf(z)) + 1.f);
        sTh[(size_t)(m0 + row) * BB + n0 + l31] = __float2half(o);
      }
    }

  } else {
    // ---------------- prep branch: leaf softmax -> fp16 B-frags -------------
    float* lps = smem;   // 3072 floats
    const int t0 = (blk - 960) * 2;
    {
      int tl = tid >> 7, l = tid & 127;
      const float* row = lo + ((size_t)(t0 + tl) * 128 + l) * CC;
      float v[CC];
      float m = -1e30f;
#pragma unroll
      for (int c = 0; c < CC; ++c) { v[c] = row[c]; m = fmaxf(m, v[c]); }
      float s = 0.f;
#pragma unroll
      for (int c = 0; c < CC; ++c) { v[c] = __expf(v[c] - m); s += v[c]; }
      float inv = 1.f / s;
      float* o = lps + (tl * 128 + l) * 12;
#pragma unroll
      for (int c = 0; c < CC; ++c) o[c] = v[c] * inv;
      o[10] = 0.f; o[11] = 0.f;
    }
    __syncthreads();

#pragma unroll
    for (int jj = 0; jj < 4; ++jj) {
      int idx = tid + 256 * jj;           // 0..1023 = (tl, s, lane)
      int tl = idx >> 9, rem = idx & 511;
      int s = rem >> 6, ln = rem & 63;
      int hf = ln >> 5, n = ln & 31;
      unsigned int wd[4];
#pragma unroll
      for (int jp = 0; jp < 4; ++jp) {
        int l0 = s * 16 + hf * 8 + jp * 2;
        float f0 = (n < CC) ? lps[(tl * 128 + l0) * 12 + n] : 0.f;
        float f1 = (n < CC) ? lps[(tl * 128 + l0 + 1) * 12 + n] : 0.f;
        wd[jp] = pkh(f0, f1);
      }
      ((uint4*)lpb)[(size_t)(t0 + tl) * 512 + s * 64 + ln] =
          make_uint4(wd[0], wd[1], wd[2], wd[3]);
    }
  }
}

// ---------------- Kernel 1b: repack sTh -> sPack[t][b][8] -------------------
// Coalesced both ways: 7x 2B loads (lanes = consecutive b), one uint4 store.
__global__ __launch_bounds__(256) void repack_kernel(
    const __half* __restrict__ sTh, __half* __restrict__ sPack) {
  int idx = blockIdx.x * 256 + threadIdx.x;   // 0..1048575
  int b = idx & (BB - 1);
  int t = idx >> 13;
  union { uint4 v; __half h[8]; } p;
#pragma unroll
  for (int d = 0; d < 7; ++d)
    p.h[d] = sTh[(size_t)(t * 7 + d) * BB + b];
  p.h[7] = __float2half(0.f);
  ((uint4*)sPack)[(size_t)t * BB + b] = p.v;
}

// ---------------- Kernel 2: main contraction via MFMA (fp16) ----------------
// grid (64 bg of 128 b, 16 tg of 8 trees); block 256 = 4 waves.
// Per t-iter: ONE coalesced dwordx4 gives s0..s6 (sv double-buffered);
// attn for all 8 trees from one attnB uint4. a-frags via __hmul2.
__global__ __launch_bounds__(256, 4) void main_kernel(
    const __half* __restrict__ sPack, const __half* __restrict__ attnB,
    const unsigned int* __restrict__ lpb, float* __restrict__ partial) {
  __shared__ float red[128 * 10];
  const int bg = blockIdx.x, tg = blockIdx.y;
  const int tid = threadIdx.x;
  const int w = tid >> 6, lane = tid & 63;
  const int half = lane >> 5;
  const int b = bg * 128 + w * 32 + (lane & 31);
  const uint4* spk = (const uint4*)sPack;

  // all 8 tree attn weights for this lane's b: one dwordx4 of fp16
  __half av[8];
  *(uint4*)av = *(const uint4*)(attnB + (size_t)b * TT + tg * 8);

  floatx16 acc;
#pragma unroll
  for (int i = 0; i < 16; ++i) acc[i] = 0.f;

  uint4 sv[2];
  sv[0] = spk[(size_t)(tg * 8) * BB + b];

#pragma unroll
  for (int it = 0; it < 8; ++it) {
    const int cur = it & 1;
    const int t = tg * 8 + it;
    // bf loads (L2-hot, hidden under the VALU block below)
    uint4 bf[8];
    const uint4* lpt = (const uint4*)lpb + (size_t)t * 512 + lane;
#pragma unroll
    for (int s = 0; s < 8; ++s) bf[s] = lpt[s * 64];
    // prefetch next iteration's s-vector
    if (it < 7) sv[cur ^ 1] = spk[(size_t)(t + 1) * BB + b];

    const __half* sh = (const __half*)&sv[cur];
    float s0 = __half2float(sh[0]), s1 = __half2float(sh[1]);
    float s2 = __half2float(sh[2]), s3 = __half2float(sh[3]);
    float s4 = __half2float(sh[4]), s5 = __half2float(sh[5]);
    float s6 = __half2float(sh[6]);
    float A  = __half2float(av[it]);

    float s0c = 1.f - s0, s1c = 1.f - s1, s2c = 1.f - s2;
    float t0 = s0 * s1, t1 = s0c * s1, t2 = s0 * s1c, t3 = s0c * s1c;
    float pl[8];
    pl[0] = t0 * s2;  pl[1] = t1 * s2;  pl[2] = t2 * s2;  pl[3] = t3 * s2;
    pl[4] = t0 * s2c; pl[5] = t1 * s2c; pl[6] = t2 * s2c; pl[7] = t3 * s2c;
    float sel3 = half ? (1.f - s3) : s3;
    float Af = A * sel3;
    float s4c = 1.f - s4, s5c = 1.f - s5;
    float as6 = Af * s6, as6c = Af * (1.f - s6);
    float u0 = s4 * s5, u1 = s4c * s5, u2 = s4 * s5c, u3 = s4c * s5c;
    float wv[8];
    wv[0] = u0 * as6;  wv[1] = u1 * as6;  wv[2] = u2 * as6;  wv[3] = u3 * as6;
    wv[4] = u0 * as6c; wv[5] = u1 * as6c; wv[6] = u2 * as6c; wv[7] = u3 * as6c;

    __half2 pl2[4];
#pragma unroll
    for (int jp = 0; jp < 4; ++jp)
      pl2[jp] = __float22half2_rn(make_float2(pl[jp * 2], pl[jp * 2 + 1]));

#pragma unroll
    for (int s = 0; s < 8; ++s) {
      __half2 w2 = __half2half2(__float2half(wv[s]));
      union { short8 v; __half2 h[4]; } a;
#pragma unroll
      for (int jp = 0; jp < 4; ++jp) a.h[jp] = __hmul2(pl2[jp], w2);
      acc = __builtin_amdgcn_mfma_f32_32x32x16_f16(
          a.v, *(const short8*)&bf[s], acc, 0, 0, 0);
    }
  }

  const int col = lane & 31;
  if (col < CC) {
#pragma unroll
    for (int r = 0; r < 16; ++r) {
      int row = (r & 3) + 8 * (r >> 2) + 4 * half;
      red[(w * 32 + row) * 10 + col] = acc[r];
    }
  }
  __syncthreads();
#pragma unroll
  for (int j = 0; j < 5; ++j) {
    int idx = tid + 256 * j;   // 0..1279
    partial[(size_t)tg * 81920 + (size_t)bg * 1280 + idx] = red[idx];
  }
}

// ---------------- Kernel 3: final reduce over 16 tree-groups ----------------
__global__ __launch_bounds__(256) void reduce_kernel(
    const float* __restrict__ partial, float* __restrict__ out) {
  int idx = blockIdx.x * 256 + threadIdx.x;  // 0..81919
  float s = 0.f;
#pragma unroll
  for (int tg = 0; tg < 16; ++tg) s += partial[(size_t)tg * 81920 + idx];
  out[idx] = s;
}

// ---------------------------------------------------------------------------
extern "C" void kernel_launch(void* const* d_in, const int* in_sizes, int n_in,
                              void* d_out, int out_size, void* d_ws, size_t ws_size,
                              hipStream_t stream) {
  const float* x    = (const float*)d_in[0];
  const float* mask = (const float*)d_in[1];
  const float* thr  = (const float*)d_in[2];
  const float* lo   = (const float*)d_in[3];
  const float* W1   = (const float*)d_in[4];
  const float* b1   = (const float*)d_in[5];
  const float* W2   = (const float*)d_in[6];
  const float* b2   = (const float*)d_in[7];
  float* out = (float*)d_out;
  float* ws  = (float*)d_ws;

  __half*       sTh     = (__half*)(ws + OFF_STH);
  __half*       attnB   = (__half*)(ws + OFF_AT);
  __half*       sPack   = (__half*)(ws + OFF_SP);
  unsigned int* LPb     = (unsigned int*)(ws + OFF_LPB);
  float*        partial = ws + OFF_PT;

  phase1_kernel<<<1024, 256, 0, stream>>>(x, mask, thr, lo, W1, b1, W2, b2,
                                          sTh, attnB, LPb);
  repack_kernel<<<4096, 256, 0, stream>>>(sTh, sPack);
  main_kernel<<<dim3(64, 16), 256, 0, stream>>>(sPack, attnB, LPb, partial);
  reduce_kernel<<<320, 256, 0, stream>>>(partial, out);
}